// Round 6
// baseline (10766.551 us; speedup 1.0000x reference)
//
#include <hip/hip_runtime.h>
#include <hip/hip_cooperative_groups.h>
#include <math.h>

namespace cg = cooperative_groups;

#define NN 65536
#define TWO_N (2 * NN)
#define VOCAB 1000
#define MD 256
#define G3 768
#define DMAX 65536
#define DCAP 128
#define NB 16
#define NT 256
#define DFIX 36
#define WGRID 1024

struct Params {
    const int* l_tokens; const int* l_parent;
    const int* r_tokens; const int* r_parent;
    const float* emb_W;
    const float* Wioux; const float* bioux;
    const float* Wiouh; const float* biouh;
    const float* Wfx;   const float* bfx;
    const float* Wfh;   const float* bfh;
    const float* Wh;    const float* bh;
    const float* Wp;    const float* bp;
    float* out;
    // workspace
    float* E_ioux;   // [VOCAB][768]  (includes bioux)
    float* E_fx;     // [VOCAB][256]  (includes bfx)
    float* h_sum;    // [NN][256]  (one tree at a time)
    float* fc_sum;   // [NN][256]
    float* c_root;   // [2][256]
    int* anc_a; int* anc_b; int* dep_a; int* dep_b;  // [2N]
    int* cnt; int* offs; int* cur;                    // [2*DMAX] (tree-major)
    int* order;                                        // [2N]
    int* maxd;                                         // [2]; flags at +8
};

union SMem {
    struct { float es[4][MD]; } e;
    struct {
        float hls[NB][MD];
        int nid[NB]; int loc[NB]; int tok[NB]; int par[NB]; int ptok[NB];
    } w;
    struct { int hcnt[2 * DCAP]; int hbase[2 * DCAP]; int hmax2[2]; } s;
    struct { float vec[2 * MD]; float red[2][NT]; } h;
};

__device__ __forceinline__ float sigmoidf_(float x) {
    return 1.0f / (1.0f + __expf(-x));
}
__device__ __forceinline__ float tanhf_(float x) {
    float ex = __expf(2.0f * x);
    return 1.0f - 2.0f / (ex + 1.0f);
}

// processes NB nodes of ONE tree; state arrays are local-indexed [NN][256]
__device__ void process_group(const Params& P, SMem& sm, int base, int cntv,
                              int t, bool fence) {
    __syncthreads();   // protect smem reuse
    if (t < NB) {
        int g = -1, loc = 0, tok = 0, par = 0, ptok = 0;
        if (t < cntv) {
            g = P.order[base + t];
            int tree = g >> 16, i = g & (NN - 1);
            const int* toks = tree ? P.r_tokens : P.l_tokens;
            const int* pars = tree ? P.r_parent : P.l_parent;
            loc = i;
            tok = toks[i];
            int pl = pars[i];
            par = pl;
            ptok = toks[pl];
        }
        sm.w.nid[t] = g; sm.w.loc[t] = loc; sm.w.tok[t] = tok;
        sm.w.par[t] = par; sm.w.ptok[t] = ptok;
    }
    __syncthreads();
    #pragma unroll
    for (int nb = 0; nb < NB; ++nb) {
        int g = sm.w.nid[nb];
        sm.w.hls[nb][t] = (g >= 0) ? P.h_sum[(size_t)sm.w.loc[nb] * MD + t] : 0.0f;
    }
    __syncthreads();

    // ---- iou = E_ioux[tok] + h_sum @ Wiouh + biouh ; thread t owns element t ----
    float ai[NB], ao[NB], au[NB];
    #pragma unroll
    for (int nb = 0; nb < NB; ++nb) { ai[nb] = 0.f; ao[nb] = 0.f; au[nb] = 0.f; }
    const float* W = P.Wiouh;
    for (int k = 0; k < MD; k += 4) {
        float wi0 = W[(k + 0) * G3 + t];
        float wi1 = W[(k + 1) * G3 + t];
        float wi2 = W[(k + 2) * G3 + t];
        float wi3 = W[(k + 3) * G3 + t];
        float wo0 = W[(k + 0) * G3 + 256 + t];
        float wo1 = W[(k + 1) * G3 + 256 + t];
        float wo2 = W[(k + 2) * G3 + 256 + t];
        float wo3 = W[(k + 3) * G3 + 256 + t];
        float wu0 = W[(k + 0) * G3 + 512 + t];
        float wu1 = W[(k + 1) * G3 + 512 + t];
        float wu2 = W[(k + 2) * G3 + 512 + t];
        float wu3 = W[(k + 3) * G3 + 512 + t];
        #pragma unroll
        for (int nb = 0; nb < NB; ++nb) {
            float4 hv = *(const float4*)&sm.w.hls[nb][k];
            ai[nb] += wi0 * hv.x; ai[nb] += wi1 * hv.y; ai[nb] += wi2 * hv.z; ai[nb] += wi3 * hv.w;
            ao[nb] += wo0 * hv.x; ao[nb] += wo1 * hv.y; ao[nb] += wo2 * hv.z; ao[nb] += wo3 * hv.w;
            au[nb] += wu0 * hv.x; au[nb] += wu1 * hv.y; au[nb] += wu2 * hv.z; au[nb] += wu3 * hv.w;
        }
    }

    // ---- gates, c, h ----
    float cv[NB];
    float b_i = P.biouh[t], b_o = P.biouh[256 + t], b_u = P.biouh[512 + t];
    __syncthreads();
    #pragma unroll
    for (int nb = 0; nb < NB; ++nb) {
        int g = sm.w.nid[nb];
        float hval = 0.0f, cval = 0.0f;
        if (g >= 0) {
            const float* Ei = P.E_ioux + (size_t)sm.w.tok[nb] * G3;
            float ig = Ei[t] + ai[nb] + b_i;
            float og = Ei[256 + t] + ao[nb] + b_o;
            float ug = Ei[512 + t] + au[nb] + b_u;
            cval = sigmoidf_(ig) * tanhf_(ug) + P.fc_sum[(size_t)sm.w.loc[nb] * MD + t];
            hval = sigmoidf_(og) * tanhf_(cval);
        }
        cv[nb] = cval;
        sm.w.hls[nb][t] = hval;   // overwrite with h
    }
    __syncthreads();

    // ---- f = sigmoid(h @ Wfh + bfh + E_fx[ptok]) ; scatter to parent ----
    float af[NB];
    #pragma unroll
    for (int nb = 0; nb < NB; ++nb) af[nb] = 0.f;
    const float* Wf = P.Wfh;
    for (int k = 0; k < MD; k += 4) {
        float wf0 = Wf[(k + 0) * MD + t];
        float wf1 = Wf[(k + 1) * MD + t];
        float wf2 = Wf[(k + 2) * MD + t];
        float wf3 = Wf[(k + 3) * MD + t];
        #pragma unroll
        for (int nb = 0; nb < NB; ++nb) {
            float4 hv = *(const float4*)&sm.w.hls[nb][k];
            af[nb] += wf0 * hv.x; af[nb] += wf1 * hv.y; af[nb] += wf2 * hv.z; af[nb] += wf3 * hv.w;
        }
    }
    float b_f = P.bfh[t];
    #pragma unroll
    for (int nb = 0; nb < NB; ++nb) {
        int g = sm.w.nid[nb];
        if (g < 0) continue;
        int i = g & (NN - 1);
        if (i == 0) {
            P.c_root[(g >> 16) * MD + t] = cv[nb];
        } else {
            float f = sigmoidf_(af[nb] + b_f + P.E_fx[(size_t)sm.w.ptok[nb] * MD + t]);
            int p = sm.w.par[nb];
            atomicAdd(&P.h_sum[(size_t)p * MD + t], sm.w.hls[nb][t]);
            atomicAdd(&P.fc_sum[(size_t)p * MD + t], f * cv[nb]);
        }
    }
    if (fence) __threadfence();
}

// ---------- shared device helpers (used by fused + fallback) ----------
__device__ void etab_body(const Params& P, SMem& sm, int t, int bid, int nblk) {
    for (int v0 = bid * 4; v0 < VOCAB; v0 += nblk * 4) {
        __syncthreads();
        #pragma unroll
        for (int r = 0; r < 4; ++r)
            sm.e.es[r][t] = (v0 + r < VOCAB) ? P.emb_W[(size_t)(v0 + r) * MD + t] : 0.f;
        __syncthreads();
        float a0[4] = {0.f,0.f,0.f,0.f}, a1[4] = {0.f,0.f,0.f,0.f};
        float a2[4] = {0.f,0.f,0.f,0.f}, a3[4] = {0.f,0.f,0.f,0.f};
        for (int k = 0; k < MD; ++k) {
            float wi = P.Wioux[k * G3 + t];
            float wo = P.Wioux[k * G3 + 256 + t];
            float wu = P.Wioux[k * G3 + 512 + t];
            float wf = P.Wfx[k * MD + t];
            #pragma unroll
            for (int r = 0; r < 4; ++r) {
                float e = sm.e.es[r][k];
                a0[r] += wi * e; a1[r] += wo * e; a2[r] += wu * e; a3[r] += wf * e;
            }
        }
        float bi = P.bioux[t], bo = P.bioux[256 + t], bu = P.bioux[512 + t], bf = P.bfx[t];
        for (int r = 0; r < 4; ++r) {
            if (v0 + r < VOCAB) {
                P.E_ioux[(size_t)(v0 + r) * G3 + t]       = a0[r] + bi;
                P.E_ioux[(size_t)(v0 + r) * G3 + 256 + t] = a1[r] + bo;
                P.E_ioux[(size_t)(v0 + r) * G3 + 512 + t] = a2[r] + bu;
                P.E_fx[(size_t)(v0 + r) * MD + t]         = a3[r] + bf;
            }
        }
        __syncthreads();
    }
}

__device__ void head_body(const Params& P, SMem& sm, int t) {
    float cl = P.c_root[t], cr = P.c_root[MD + t];
    sm.h.vec[t] = cl * cr;
    sm.h.vec[MD + t] = fabsf(cl - cr);
    __syncthreads();
    float acc = 0.f;
    for (int j = 0; j < 2 * MD; ++j) acc += sm.h.vec[j] * P.Wh[(size_t)j * MD + t];
    float hid = sigmoidf_(acc + P.bh[t]);
    sm.h.red[0][t] = hid * P.Wp[t * 2 + 0];
    sm.h.red[1][t] = hid * P.Wp[t * 2 + 1];
    __syncthreads();
    for (int s = 128; s > 0; s >>= 1) {
        if (t < s) {
            sm.h.red[0][t] += sm.h.red[0][t + s];
            sm.h.red[1][t] += sm.h.red[1][t + s];
        }
        __syncthreads();
    }
    if (t == 0) {
        float l0 = sm.h.red[0][0] + P.bp[0];
        float l1 = sm.h.red[1][0] + P.bp[1];
        float mx = fmaxf(l0, l1);
        float e0 = __expf(l0 - mx), e1 = __expf(l1 - mx);
        float inv = 1.0f / (e0 + e1);
        P.out[0] = e0 * inv;
        P.out[1] = e1 * inv;
    }
}

// =======================================================================
// FUSED cooperative kernel: everything in one launch, weights stay warm.
// =======================================================================
__global__ __launch_bounds__(NT, 4) void fused_kernel(Params P) {
    cg::grid_group grid = cg::this_grid();
    __shared__ SMem sm;
    const int t = threadIdx.x;
    const int bid = blockIdx.x;
    const int nblk = gridDim.x;
    const int gsize = nblk * NT;
    const int gtid = bid * NT + t;
    int* flags = P.maxd + 2;   // 16 ints, zeroed below

    // ---- phase A: zero state + init anc/dep + zero counters ----
    {
        float4 z = make_float4(0.f, 0.f, 0.f, 0.f);
        float4* hz = (float4*)P.h_sum;
        float4* fz = (float4*)P.fc_sum;
        int n4 = NN * (MD / 4);
        for (int i = gtid; i < n4; i += gsize) { hz[i] = z; fz[i] = z; }
        for (int i = gtid; i < 2 * DMAX; i += gsize) { P.cnt[i] = 0; P.cur[i] = 0; }
        if (gtid < 2) P.maxd[gtid] = 0;
        if (gtid >= 2 && gtid < 18) flags[gtid - 2] = 0;
        for (int g = gtid; g < TWO_N; g += gsize) {
            int tree = g >> 16, i = g & (NN - 1);
            if (i == 0) { P.anc_a[g] = g; P.dep_a[g] = 0; }
            else {
                const int* par = tree ? P.r_parent : P.l_parent;
                P.anc_a[g] = (tree << 16) | par[i];
                P.dep_a[g] = 1;
            }
        }
    }
    // ---- phase B: E tables ----
    etab_body(P, sm, t, bid, nblk);
    grid.sync();

    // ---- phase C: pointer doubling with early exit ----
    {
        int* pa = P.anc_a; int* pd = P.dep_a; int* qa = P.anc_b; int* qd = P.dep_b;
        for (int it = 0; it < 16; ++it) {
            int changed = 0;
            for (int g = gtid; g < TWO_N; g += gsize) {
                int a = pa[g];
                int da = pd[a];
                qd[g] = pd[g] + da;
                qa[g] = pa[a];
                changed |= (da != 0);
            }
            if (changed) flags[it] = 1;   // racy same-value write: fine
            grid.sync();
            int* tmp = pa; pa = qa; qa = tmp;
            tmp = pd; pd = qd; qd = tmp;
            if (flags[it] == 0) break;    // uniform decision post-sync
        }
        // final depths in pd; stash pointer choice by copying ref for later phases
        // (store which buffer via flags[15]? simpler: copy into dep_a if needed)
        if (pd != P.dep_a) {
            for (int g = gtid; g < TWO_N; g += gsize) P.dep_a[g] = pd[g];
        }
    }
    grid.sync();

    // ---- phase D: hist (LDS pre-reduced) ----
    {
        for (int i = t; i < 2 * DCAP; i += NT) sm.s.hcnt[i] = 0;
        if (t < 2) sm.s.hmax2[t] = 0;
        __syncthreads();
        for (int g = gtid; g < TWO_N; g += gsize) {
            int tree = g >> 16;
            int d = P.dep_a[g];
            if (d < DCAP) {
                atomicAdd(&sm.s.hcnt[tree * DCAP + d], 1);
                atomicMax(&sm.s.hmax2[tree], d);
            } else {
                atomicAdd(&P.cnt[tree * DMAX + d], 1);
                atomicMax(&P.maxd[tree], d);
            }
        }
        __syncthreads();
        for (int i = t; i < 2 * DCAP; i += NT) {
            int c = sm.s.hcnt[i];
            if (c > 0) atomicAdd(&P.cnt[(i >= DCAP ? DMAX : 0) + (i & (DCAP - 1))], c);
        }
        if (t < 2) atomicMax(&P.maxd[t], sm.s.hmax2[t]);
    }
    grid.sync();

    // ---- prefix (tiny serial, block 0) ----
    if (bid == 0 && t < 2) {
        int tree = t;
        int run = tree * NN;
        int md = P.maxd[tree];
        for (int d = 0; d <= md; ++d) {
            P.offs[tree * DMAX + d] = run;
            run += P.cnt[tree * DMAX + d];
        }
    }
    grid.sync();

    // ---- scatter (block-level reservation) ----
    {
        for (int i = t; i < 2 * DCAP; i += NT) sm.s.hcnt[i] = 0;
        __syncthreads();
        for (int g = gtid; g < TWO_N; g += gsize) {
            int tree = g >> 16;
            int d = P.dep_a[g];
            if (d < DCAP) atomicAdd(&sm.s.hcnt[tree * DCAP + d], 1);
        }
        __syncthreads();
        for (int i = t; i < 2 * DCAP; i += NT) {
            int c = sm.s.hcnt[i];
            if (c > 0) {
                int idx = (i >= DCAP ? DMAX : 0) + (i & (DCAP - 1));
                sm.s.hbase[i] = P.offs[idx] + atomicAdd(&P.cur[idx], c);
            }
            sm.s.hcnt[i] = 0;
        }
        __syncthreads();
        for (int g = gtid; g < TWO_N; g += gsize) {
            int tree = g >> 16;
            int d = P.dep_a[g];
            if (d < DCAP) {
                int b = tree * DCAP + d;
                int pos = atomicAdd(&sm.s.hcnt[b], 1);
                P.order[sm.s.hbase[b] + pos] = g;
            } else {
                int idx = tree * DMAX + d;
                int pos = atomicAdd(&P.cur[idx], 1);
                P.order[P.offs[idx] + pos] = g;
            }
        }
    }
    grid.sync();

    // ---- depth ladders, tree 0 then tree 1 (state array reused) ----
    for (int tree = 0; tree < 2; ++tree) {
        int md = P.maxd[tree];
        for (int d = md; d >= 0; --d) {
            int nwave = P.cnt[tree * DMAX + d];
            int start = P.offs[tree * DMAX + d];
            int ngroups = (nwave + NB - 1) / NB;
            for (int grp = bid; grp < ngroups; grp += nblk) {
                int base = grp * NB;
                int cntv = nwave - base; if (cntv > NB) cntv = NB;
                process_group(P, sm, start + base, cntv, t, false);
            }
            grid.sync();
        }
        if (tree == 0) {   // re-zero state for tree 1
            float4 z = make_float4(0.f, 0.f, 0.f, 0.f);
            float4* hz = (float4*)P.h_sum;
            float4* fz = (float4*)P.fc_sum;
            int n4 = NN * (MD / 4);
            for (int i = gtid; i < n4; i += gsize) { hz[i] = z; fz[i] = z; }
            grid.sync();
        }
    }

    // ---- head ----
    if (bid == 0) head_body(P, sm, t);
}

// =======================================================================
// Fallback path (round-5 proven multi-launch) — used only if coop fails.
// =======================================================================
__global__ void init_anc_kernel(Params P) {
    int stride = gridDim.x * blockDim.x;
    for (int g = blockIdx.x * blockDim.x + threadIdx.x; g < TWO_N; g += stride) {
        int tree = g >> 16, i = g & (NN - 1);
        if (i == 0) { P.anc_a[g] = g; P.dep_a[g] = 0; }
        else {
            const int* par = tree ? P.r_parent : P.l_parent;
            P.anc_a[g] = (tree << 16) | par[i];
            P.dep_a[g] = 1;
        }
    }
}

__global__ void etab_kernel(Params P) {
    __shared__ SMem sm;
    etab_body(P, sm, threadIdx.x, blockIdx.x, gridDim.x);
}

__global__ void jump_kernel(const int* __restrict__ pa, const int* __restrict__ pd,
                            int* __restrict__ qa, int* __restrict__ qd) {
    int stride = gridDim.x * blockDim.x;
    for (int g = blockIdx.x * blockDim.x + threadIdx.x; g < TWO_N; g += stride) {
        int a = pa[g];
        qd[g] = pd[g] + pd[a];
        qa[g] = pa[a];
    }
}

__global__ void hist_kernel(Params P) {
    __shared__ int hcnt[2 * DCAP];
    __shared__ int hmax[2];
    int t = threadIdx.x;
    for (int i = t; i < 2 * DCAP; i += NT) hcnt[i] = 0;
    if (t < 2) hmax[t] = 0;
    __syncthreads();
    int stride = gridDim.x * blockDim.x;
    for (int g = blockIdx.x * blockDim.x + t; g < TWO_N; g += stride) {
        int tree = g >> 16;
        int d = P.dep_a[g];
        if (d < DCAP) {
            atomicAdd(&hcnt[tree * DCAP + d], 1);
            atomicMax(&hmax[tree], d);
        } else {
            atomicAdd(&P.cnt[tree * DMAX + d], 1);
            atomicMax(&P.maxd[tree], d);
        }
    }
    __syncthreads();
    for (int i = t; i < 2 * DCAP; i += NT) {
        int c = hcnt[i];
        if (c > 0) atomicAdd(&P.cnt[(i >= DCAP ? DMAX : 0) + (i & (DCAP - 1))], c);
    }
    if (t < 2) atomicMax(&P.maxd[t], hmax[t]);
}

__global__ void prefix_kernel(Params P) {
    if (threadIdx.x == 0 && blockIdx.x == 0) {
        for (int tree = 0; tree < 2; ++tree) {
            int run = tree * NN;
            int md = P.maxd[tree];
            for (int d = 0; d <= md; ++d) {
                P.offs[tree * DMAX + d] = run;
                run += P.cnt[tree * DMAX + d];
            }
        }
    }
}

__global__ void scatter_kernel(Params P) {
    __shared__ int hcnt[2 * DCAP];
    __shared__ int hbase[2 * DCAP];
    int t = threadIdx.x;
    for (int i = t; i < 2 * DCAP; i += NT) hcnt[i] = 0;
    __syncthreads();
    int stride = gridDim.x * blockDim.x;
    for (int g = blockIdx.x * blockDim.x + t; g < TWO_N; g += stride) {
        int tree = g >> 16;
        int d = P.dep_a[g];
        if (d < DCAP) atomicAdd(&hcnt[tree * DCAP + d], 1);
    }
    __syncthreads();
    for (int i = t; i < 2 * DCAP; i += NT) {
        int c = hcnt[i];
        if (c > 0) {
            int idx = (i >= DCAP ? DMAX : 0) + (i & (DCAP - 1));
            hbase[i] = P.offs[idx] + atomicAdd(&P.cur[idx], c);
        }
        hcnt[i] = 0;
    }
    __syncthreads();
    for (int g = blockIdx.x * blockDim.x + t; g < TWO_N; g += stride) {
        int tree = g >> 16;
        int d = P.dep_a[g];
        if (d < DCAP) {
            int b = tree * DCAP + d;
            int pos = atomicAdd(&hcnt[b], 1);
            P.order[hbase[b] + pos] = g;
        } else {
            int idx = tree * DMAX + d;
            int pos = atomicAdd(&P.cur[idx], 1);
            P.order[P.offs[idx] + pos] = g;
        }
    }
}

__global__ __launch_bounds__(NT, 2) void deep_kernel(Params P, int tree) {
    __shared__ SMem sm;
    int t = threadIdx.x;
    int md = P.maxd[tree];
    for (int d = md; d >= DFIX; --d) {
        int nwave = P.cnt[tree * DMAX + d];
        int start = P.offs[tree * DMAX + d];
        int ngroups = (nwave + NB - 1) / NB;
        for (int grp = 0; grp < ngroups; ++grp) {
            int base = grp * NB;
            int cntv = nwave - base; if (cntv > NB) cntv = NB;
            process_group(P, sm, start + base, cntv, t, true);
        }
        __syncthreads();
    }
}

__global__ __launch_bounds__(NT, 4) void wave_kernel(Params P, int tree, int d) {
    __shared__ SMem sm;
    int t = threadIdx.x;
    int nwave = P.cnt[tree * DMAX + d];
    if (nwave == 0) return;
    int start = P.offs[tree * DMAX + d];
    int ngroups = (nwave + NB - 1) / NB;
    for (int grp = blockIdx.x; grp < ngroups; grp += gridDim.x) {
        int base = grp * NB;
        int cntv = nwave - base; if (cntv > NB) cntv = NB;
        process_group(P, sm, start + base, cntv, t, false);
    }
}

__global__ void head_kernel(Params P) {
    __shared__ SMem sm;
    head_body(P, sm, threadIdx.x);
}

extern "C" void kernel_launch(void* const* d_in, const int* in_sizes, int n_in,
                              void* d_out, int out_size, void* d_ws, size_t ws_size,
                              hipStream_t stream) {
    Params P;
    P.l_tokens = (const int*)d_in[0];
    P.l_parent = (const int*)d_in[1];
    P.r_tokens = (const int*)d_in[2];
    P.r_parent = (const int*)d_in[3];
    P.emb_W = (const float*)d_in[4];
    P.Wioux = (const float*)d_in[5];
    P.bioux = (const float*)d_in[6];
    P.Wiouh = (const float*)d_in[7];
    P.biouh = (const float*)d_in[8];
    P.Wfx   = (const float*)d_in[9];
    P.bfx   = (const float*)d_in[10];
    P.Wfh   = (const float*)d_in[11];
    P.bfh   = (const float*)d_in[12];
    P.Wh    = (const float*)d_in[13];
    P.bh    = (const float*)d_in[14];
    P.Wp    = (const float*)d_in[15];
    P.bp    = (const float*)d_in[16];
    P.out   = (float*)d_out;

    char* w = (char*)d_ws;
    auto alloc = [&](size_t bytes) {
        char* r = w;
        w += (bytes + 255) & ~(size_t)255;
        return r;
    };
    // total ~142 MB
    P.E_ioux = (float*)alloc((size_t)VOCAB * G3 * 4);
    P.E_fx   = (float*)alloc((size_t)VOCAB * MD * 4);
    P.h_sum  = (float*)alloc((size_t)NN * MD * 4);
    P.fc_sum = (float*)alloc((size_t)NN * MD * 4);
    P.c_root = (float*)alloc(2 * MD * 4);
    P.anc_a  = (int*)alloc((size_t)TWO_N * 4);
    P.anc_b  = (int*)alloc((size_t)TWO_N * 4);
    P.dep_a  = (int*)alloc((size_t)TWO_N * 4);
    P.dep_b  = (int*)alloc((size_t)TWO_N * 4);
    P.cnt    = (int*)alloc((size_t)2 * DMAX * 4);
    P.offs   = (int*)alloc((size_t)2 * DMAX * 4);
    P.cur    = (int*)alloc((size_t)2 * DMAX * 4);
    P.order  = (int*)alloc((size_t)TWO_N * 4);
    P.maxd   = (int*)alloc(256);   // maxd[0..1] + flags[16]

    // ---- try the fused cooperative path ----
    int blocksPerCU = 0;
    hipError_t oe = hipOccupancyMaxActiveBlocksPerMultiprocessor(
        &blocksPerCU, (const void*)fused_kernel, NT, 0);
    hipError_t ce = hipErrorUnknown;
    if (oe == hipSuccess && blocksPerCU > 0) {
        int bpc = blocksPerCU < 4 ? blocksPerCU : 4;
        dim3 grid(256 * bpc), block(NT);
        void* args[] = { &P };
        ce = hipLaunchCooperativeKernel((void*)fused_kernel, grid, block,
                                        args, 0, stream);
    }
    if (ce == hipSuccess) return;

    // ---- fallback: proven multi-launch path ----
    hipMemsetAsync(P.cnt,  0, (size_t)2 * DMAX * 4, stream);
    hipMemsetAsync(P.cur,  0, (size_t)2 * DMAX * 4, stream);
    hipMemsetAsync(P.maxd, 0, 8, stream);

    init_anc_kernel<<<256, NT, 0, stream>>>(P);
    etab_kernel<<<250, NT, 0, stream>>>(P);

    int* pa = P.anc_a; int* pd = P.dep_a; int* qa = P.anc_b; int* qd = P.dep_b;
    for (int it = 0; it < 16; ++it) {
        jump_kernel<<<256, NT, 0, stream>>>(pa, pd, qa, qd);
        int* tmp = pa; pa = qa; qa = tmp;
        tmp = pd; pd = qd; qd = tmp;
    }

    hist_kernel<<<64, NT, 0, stream>>>(P);
    prefix_kernel<<<1, 64, 0, stream>>>(P);
    scatter_kernel<<<64, NT, 0, stream>>>(P);

    for (int tree = 0; tree < 2; ++tree) {
        hipMemsetAsync(P.h_sum,  0, (size_t)NN * MD * 4, stream);
        hipMemsetAsync(P.fc_sum, 0, (size_t)NN * MD * 4, stream);
        deep_kernel<<<1, NT, 0, stream>>>(P, tree);
        for (int d = DFIX - 1; d >= 0; --d) {
            wave_kernel<<<WGRID, NT, 0, stream>>>(P, tree, d);
        }
    }
    head_kernel<<<1, NT, 0, stream>>>(P);
}

// Round 7
// 9408.741 us; speedup vs baseline: 1.1443x; 1.1443x over previous
//
#include <hip/hip_runtime.h>
#include <math.h>

#define NN 65536
#define TWO_N (2 * NN)
#define VOCAB 1000
#define MD 256
#define G3 768
#define DMAX 65536
#define DCAP 128
#define NB 16
#define NT 256
#define NBLK 256
#define GSZ 16
#define NGRP 16

struct Params {
    const int* l_tokens; const int* l_parent;
    const int* r_tokens; const int* r_parent;
    const float* emb_W;
    const float* Wioux; const float* bioux;
    const float* Wiouh; const float* biouh;
    const float* Wfx;   const float* bfx;
    const float* Wfh;   const float* bfh;
    const float* Wh;    const float* bh;
    const float* Wp;    const float* bp;
    float* out;
    // workspace
    float* E_ioux;   // [VOCAB][768]
    float* E_fx;     // [VOCAB][256]
    float* h_sum;    // [NN][256]  (one tree at a time)
    float* fc_sum;   // [NN][256]
    float* c_root;   // [2][256]
    int* anc_a; int* anc_b; int* dep_a; int* dep_b;  // [2N]
    int* cnt; int* offs; int* cur;                    // [2*DMAX]
    int* order;                                        // [2N]
    int* maxd;                                         // [2] + flags[16]
    int* bar;                                          // barrier region (memset 0)
};

union SMem {
    struct { float es[4][MD]; } e;
    struct {
        float hls[NB][MD];
        int nid[NB]; int loc[NB]; int tok[NB]; int par[NB]; int ptok[NB];
    } w;
    struct { int hcnt[2 * DCAP]; int hbase[2 * DCAP]; int hmax2[2]; } s;
    struct { float vec[2 * MD]; float red[2][NT]; } h;
};

__device__ __forceinline__ float sigmoidf_(float x) {
    return 1.0f / (1.0f + __expf(-x));
}
__device__ __forceinline__ float tanhf_(float x) {
    float ex = __expf(2.0f * x);
    return 1.0f - 2.0f / (ex + 1.0f);
}

// ---- two-level monotonic grid barrier: 16 groups x 16 blocks, spaced lines ----
__device__ __forceinline__ int aload_(int* p) {
    return __hip_atomic_load(p, __ATOMIC_RELAXED, __HIP_MEMORY_SCOPE_AGENT);
}
__device__ void gbarrier(int* bar, int bid, int ep) {
    __syncthreads();
    if (threadIdx.x == 0) {
        __builtin_amdgcn_fence(__ATOMIC_RELEASE, "agent");
        int g = bid >> 4;                    // group id 0..15
        int* grpcnt = bar + g * 32;          // 128B-spaced group counters
        int* rootcnt = bar + NGRP * 32;      // root counter
        int* bcast  = bar + (NGRP + 1) * 32 + g * 32;   // per-group release word
        int a = __hip_atomic_fetch_add(grpcnt, 1, __ATOMIC_RELAXED,
                                       __HIP_MEMORY_SCOPE_AGENT);
        if (a == GSZ * ep - 1) {             // last of my group this episode
            int r = __hip_atomic_fetch_add(rootcnt, 1, __ATOMIC_RELAXED,
                                           __HIP_MEMORY_SCOPE_AGENT);
            if (r == NGRP * ep - 1) {        // last overall: release all groups
                for (int j = 0; j < NGRP; ++j)
                    __hip_atomic_store(bar + (NGRP + 1) * 32 + j * 32, ep,
                                       __ATOMIC_RELAXED, __HIP_MEMORY_SCOPE_AGENT);
            } else {
                while (aload_(bcast) < ep) __builtin_amdgcn_s_sleep(2);
            }
        } else {
            while (aload_(bcast) < ep) __builtin_amdgcn_s_sleep(2);
        }
        __builtin_amdgcn_fence(__ATOMIC_ACQUIRE, "agent");
    }
    __syncthreads();
}

// processes NB nodes of ONE tree; state arrays are local-indexed [NN][256]
__device__ void process_group(const Params& P, SMem& sm, int base, int cntv, int t) {
    __syncthreads();
    if (t < NB) {
        int g = -1, loc = 0, tok = 0, par = 0, ptok = 0;
        if (t < cntv) {
            g = P.order[base + t];
            int tree = g >> 16, i = g & (NN - 1);
            const int* toks = tree ? P.r_tokens : P.l_tokens;
            const int* pars = tree ? P.r_parent : P.l_parent;
            loc = i;
            tok = toks[i];
            int pl = pars[i];
            par = pl;
            ptok = toks[pl];
        }
        sm.w.nid[t] = g; sm.w.loc[t] = loc; sm.w.tok[t] = tok;
        sm.w.par[t] = par; sm.w.ptok[t] = ptok;
    }
    __syncthreads();
    #pragma unroll
    for (int nb = 0; nb < NB; ++nb) {
        int g = sm.w.nid[nb];
        sm.w.hls[nb][t] = (g >= 0) ? P.h_sum[(size_t)sm.w.loc[nb] * MD + t] : 0.0f;
    }
    __syncthreads();

    // ---- iou = E_ioux[tok] + h_sum @ Wiouh + biouh ----
    float ai[NB], ao[NB], au[NB];
    #pragma unroll
    for (int nb = 0; nb < NB; ++nb) { ai[nb] = 0.f; ao[nb] = 0.f; au[nb] = 0.f; }
    const float* W = P.Wiouh;
    for (int k = 0; k < MD; k += 4) {
        float wi0 = W[(k + 0) * G3 + t];
        float wi1 = W[(k + 1) * G3 + t];
        float wi2 = W[(k + 2) * G3 + t];
        float wi3 = W[(k + 3) * G3 + t];
        float wo0 = W[(k + 0) * G3 + 256 + t];
        float wo1 = W[(k + 1) * G3 + 256 + t];
        float wo2 = W[(k + 2) * G3 + 256 + t];
        float wo3 = W[(k + 3) * G3 + 256 + t];
        float wu0 = W[(k + 0) * G3 + 512 + t];
        float wu1 = W[(k + 1) * G3 + 512 + t];
        float wu2 = W[(k + 2) * G3 + 512 + t];
        float wu3 = W[(k + 3) * G3 + 512 + t];
        #pragma unroll
        for (int nb = 0; nb < NB; ++nb) {
            float4 hv = *(const float4*)&sm.w.hls[nb][k];
            ai[nb] += wi0 * hv.x; ai[nb] += wi1 * hv.y; ai[nb] += wi2 * hv.z; ai[nb] += wi3 * hv.w;
            ao[nb] += wo0 * hv.x; ao[nb] += wo1 * hv.y; ao[nb] += wo2 * hv.z; ao[nb] += wo3 * hv.w;
            au[nb] += wu0 * hv.x; au[nb] += wu1 * hv.y; au[nb] += wu2 * hv.z; au[nb] += wu3 * hv.w;
        }
    }

    // ---- gates, c, h ----
    float cv[NB];
    float b_i = P.biouh[t], b_o = P.biouh[256 + t], b_u = P.biouh[512 + t];
    __syncthreads();
    #pragma unroll
    for (int nb = 0; nb < NB; ++nb) {
        int g = sm.w.nid[nb];
        float hval = 0.0f, cval = 0.0f;
        if (g >= 0) {
            const float* Ei = P.E_ioux + (size_t)sm.w.tok[nb] * G3;
            float ig = Ei[t] + ai[nb] + b_i;
            float og = Ei[256 + t] + ao[nb] + b_o;
            float ug = Ei[512 + t] + au[nb] + b_u;
            cval = sigmoidf_(ig) * tanhf_(ug) + P.fc_sum[(size_t)sm.w.loc[nb] * MD + t];
            hval = sigmoidf_(og) * tanhf_(cval);
        }
        cv[nb] = cval;
        sm.w.hls[nb][t] = hval;
    }
    __syncthreads();

    // ---- f = sigmoid(h @ Wfh + bfh + E_fx[ptok]) ; scatter to parent ----
    float af[NB];
    #pragma unroll
    for (int nb = 0; nb < NB; ++nb) af[nb] = 0.f;
    const float* Wf = P.Wfh;
    for (int k = 0; k < MD; k += 4) {
        float wf0 = Wf[(k + 0) * MD + t];
        float wf1 = Wf[(k + 1) * MD + t];
        float wf2 = Wf[(k + 2) * MD + t];
        float wf3 = Wf[(k + 3) * MD + t];
        #pragma unroll
        for (int nb = 0; nb < NB; ++nb) {
            float4 hv = *(const float4*)&sm.w.hls[nb][k];
            af[nb] += wf0 * hv.x; af[nb] += wf1 * hv.y; af[nb] += wf2 * hv.z; af[nb] += wf3 * hv.w;
        }
    }
    float b_f = P.bfh[t];
    #pragma unroll
    for (int nb = 0; nb < NB; ++nb) {
        int g = sm.w.nid[nb];
        if (g < 0) continue;
        int i = g & (NN - 1);
        if (i == 0) {
            P.c_root[(g >> 16) * MD + t] = cv[nb];
        } else {
            float f = sigmoidf_(af[nb] + b_f + P.E_fx[(size_t)sm.w.ptok[nb] * MD + t]);
            int p = sm.w.par[nb];
            atomicAdd(&P.h_sum[(size_t)p * MD + t], sm.w.hls[nb][t]);
            atomicAdd(&P.fc_sum[(size_t)p * MD + t], f * cv[nb]);
        }
    }
}

__device__ void etab_body(const Params& P, SMem& sm, int t, int bid, int nblk) {
    for (int v0 = bid * 4; v0 < VOCAB; v0 += nblk * 4) {
        __syncthreads();
        #pragma unroll
        for (int r = 0; r < 4; ++r)
            sm.e.es[r][t] = (v0 + r < VOCAB) ? P.emb_W[(size_t)(v0 + r) * MD + t] : 0.f;
        __syncthreads();
        float a0[4] = {0.f,0.f,0.f,0.f}, a1[4] = {0.f,0.f,0.f,0.f};
        float a2[4] = {0.f,0.f,0.f,0.f}, a3[4] = {0.f,0.f,0.f,0.f};
        for (int k = 0; k < MD; ++k) {
            float wi = P.Wioux[k * G3 + t];
            float wo = P.Wioux[k * G3 + 256 + t];
            float wu = P.Wioux[k * G3 + 512 + t];
            float wf = P.Wfx[k * MD + t];
            #pragma unroll
            for (int r = 0; r < 4; ++r) {
                float e = sm.e.es[r][k];
                a0[r] += wi * e; a1[r] += wo * e; a2[r] += wu * e; a3[r] += wf * e;
            }
        }
        float bi = P.bioux[t], bo = P.bioux[256 + t], bu = P.bioux[512 + t], bf = P.bfx[t];
        for (int r = 0; r < 4; ++r) {
            if (v0 + r < VOCAB) {
                P.E_ioux[(size_t)(v0 + r) * G3 + t]       = a0[r] + bi;
                P.E_ioux[(size_t)(v0 + r) * G3 + 256 + t] = a1[r] + bo;
                P.E_ioux[(size_t)(v0 + r) * G3 + 512 + t] = a2[r] + bu;
                P.E_fx[(size_t)(v0 + r) * MD + t]         = a3[r] + bf;
            }
        }
        __syncthreads();
    }
}

__device__ void head_body(const Params& P, SMem& sm, int t) {
    float cl = P.c_root[t], cr = P.c_root[MD + t];
    sm.h.vec[t] = cl * cr;
    sm.h.vec[MD + t] = fabsf(cl - cr);
    __syncthreads();
    float acc = 0.f;
    for (int j = 0; j < 2 * MD; ++j) acc += sm.h.vec[j] * P.Wh[(size_t)j * MD + t];
    float hid = sigmoidf_(acc + P.bh[t]);
    sm.h.red[0][t] = hid * P.Wp[t * 2 + 0];
    sm.h.red[1][t] = hid * P.Wp[t * 2 + 1];
    __syncthreads();
    for (int s = 128; s > 0; s >>= 1) {
        if (t < s) {
            sm.h.red[0][t] += sm.h.red[0][t + s];
            sm.h.red[1][t] += sm.h.red[1][t + s];
        }
        __syncthreads();
    }
    if (t == 0) {
        float l0 = sm.h.red[0][0] + P.bp[0];
        float l1 = sm.h.red[1][0] + P.bp[1];
        float mx = fmaxf(l0, l1);
        float e0 = __expf(l0 - mx), e1 = __expf(l1 - mx);
        float inv = 1.0f / (e0 + e1);
        P.out[0] = e0 * inv;
        P.out[1] = e1 * inv;
    }
}

// =======================================================================
// Persistent fused kernel: 256 blocks (all co-resident), custom barrier.
// =======================================================================
__global__ __launch_bounds__(NT, 4) void fused_kernel(Params P) {
    __shared__ SMem sm;
    const int t = threadIdx.x;
    const int bid = blockIdx.x;
    const int gsize = NBLK * NT;
    const int gtid = bid * NT + t;
    int* flags = P.maxd + 2;
    int ep = 0;

    // ---- phase A: zero state & counters, init anc/dep ----
    {
        float4 z = make_float4(0.f, 0.f, 0.f, 0.f);
        float4* hz = (float4*)P.h_sum;
        float4* fz = (float4*)P.fc_sum;
        int n4 = NN * (MD / 4);
        for (int i = gtid; i < n4; i += gsize) { hz[i] = z; fz[i] = z; }
        for (int i = gtid; i < 2 * DMAX; i += gsize) { P.cnt[i] = 0; P.cur[i] = 0; }
        if (gtid < 2) P.maxd[gtid] = 0;
        if (gtid >= 2 && gtid < 18) flags[gtid - 2] = 0;
        for (int g = gtid; g < TWO_N; g += gsize) {
            int tree = g >> 16, i = g & (NN - 1);
            if (i == 0) { P.anc_a[g] = g; P.dep_a[g] = 0; }
            else {
                const int* par = tree ? P.r_parent : P.l_parent;
                P.anc_a[g] = (tree << 16) | par[i];
                P.dep_a[g] = 1;
            }
        }
    }
    // ---- phase B: E tables ----
    etab_body(P, sm, t, bid, NBLK);
    gbarrier(P.bar, bid, ++ep);

    // ---- phase C: pointer doubling, early exit ----
    {
        int* pa = P.anc_a; int* pd = P.dep_a; int* qa = P.anc_b; int* qd = P.dep_b;
        for (int it = 0; it < 16; ++it) {
            int changed = 0;
            for (int g = gtid; g < TWO_N; g += gsize) {
                int a = pa[g];
                int da = pd[a];
                qd[g] = pd[g] + da;
                qa[g] = pa[a];
                changed |= (da != 0);
            }
            if (changed) flags[it] = 1;
            gbarrier(P.bar, bid, ++ep);
            int* tmp = pa; pa = qa; qa = tmp;
            tmp = pd; pd = qd; qd = tmp;
            if (flags[it] == 0) break;    // uniform
        }
        if (pd != P.dep_a) {
            for (int g = gtid; g < TWO_N; g += gsize) P.dep_a[g] = pd[g];
            gbarrier(P.bar, bid, ++ep);
        }
    }

    // ---- phase D: hist ----
    {
        for (int i = t; i < 2 * DCAP; i += NT) sm.s.hcnt[i] = 0;
        if (t < 2) sm.s.hmax2[t] = 0;
        __syncthreads();
        for (int g = gtid; g < TWO_N; g += gsize) {
            int tree = g >> 16;
            int d = P.dep_a[g];
            if (d < DCAP) {
                atomicAdd(&sm.s.hcnt[tree * DCAP + d], 1);
                atomicMax(&sm.s.hmax2[tree], d);
            } else {
                atomicAdd(&P.cnt[tree * DMAX + d], 1);
                atomicMax(&P.maxd[tree], d);
            }
        }
        __syncthreads();
        for (int i = t; i < 2 * DCAP; i += NT) {
            int c = sm.s.hcnt[i];
            if (c > 0) atomicAdd(&P.cnt[(i >= DCAP ? DMAX : 0) + (i & (DCAP - 1))], c);
        }
        if (t < 2) atomicMax(&P.maxd[t], sm.s.hmax2[t]);
    }
    gbarrier(P.bar, bid, ++ep);

    // ---- prefix (block 0) ----
    if (bid == 0 && t < 2) {
        int tree = t;
        int run = tree * NN;
        int md = P.maxd[tree];
        for (int d = 0; d <= md; ++d) {
            P.offs[tree * DMAX + d] = run;
            run += P.cnt[tree * DMAX + d];
        }
    }
    gbarrier(P.bar, bid, ++ep);

    // ---- scatter ----
    {
        for (int i = t; i < 2 * DCAP; i += NT) sm.s.hcnt[i] = 0;
        __syncthreads();
        for (int g = gtid; g < TWO_N; g += gsize) {
            int tree = g >> 16;
            int d = P.dep_a[g];
            if (d < DCAP) atomicAdd(&sm.s.hcnt[tree * DCAP + d], 1);
        }
        __syncthreads();
        for (int i = t; i < 2 * DCAP; i += NT) {
            int c = sm.s.hcnt[i];
            if (c > 0) {
                int idx = (i >= DCAP ? DMAX : 0) + (i & (DCAP - 1));
                sm.s.hbase[i] = P.offs[idx] + atomicAdd(&P.cur[idx], c);
            }
            sm.s.hcnt[i] = 0;
        }
        __syncthreads();
        for (int g = gtid; g < TWO_N; g += gsize) {
            int tree = g >> 16;
            int d = P.dep_a[g];
            if (d < DCAP) {
                int b = tree * DCAP + d;
                int pos = atomicAdd(&sm.s.hcnt[b], 1);
                P.order[sm.s.hbase[b] + pos] = g;
            } else {
                int idx = tree * DMAX + d;
                int pos = atomicAdd(&P.cur[idx], 1);
                P.order[P.offs[idx] + pos] = g;
            }
        }
    }
    gbarrier(P.bar, bid, ++ep);

    // ---- depth ladders ----
    for (int tree = 0; tree < 2; ++tree) {
        int md = P.maxd[tree];
        for (int d = md; d >= 0; --d) {
            int nwave = P.cnt[tree * DMAX + d];
            int start = P.offs[tree * DMAX + d];
            int ngroups = (nwave + NB - 1) / NB;
            for (int grp = bid; grp < ngroups; grp += NBLK) {
                int base = grp * NB;
                int cntv = nwave - base; if (cntv > NB) cntv = NB;
                process_group(P, sm, start + base, cntv, t);
            }
            gbarrier(P.bar, bid, ++ep);
        }
        if (tree == 0) {
            float4 z = make_float4(0.f, 0.f, 0.f, 0.f);
            float4* hz = (float4*)P.h_sum;
            float4* fz = (float4*)P.fc_sum;
            int n4 = NN * (MD / 4);
            for (int i = gtid; i < n4; i += gsize) { hz[i] = z; fz[i] = z; }
            gbarrier(P.bar, bid, ++ep);
        }
    }

    // ---- head ----
    if (bid == 0) head_body(P, sm, t);
}

extern "C" void kernel_launch(void* const* d_in, const int* in_sizes, int n_in,
                              void* d_out, int out_size, void* d_ws, size_t ws_size,
                              hipStream_t stream) {
    Params P;
    P.l_tokens = (const int*)d_in[0];
    P.l_parent = (const int*)d_in[1];
    P.r_tokens = (const int*)d_in[2];
    P.r_parent = (const int*)d_in[3];
    P.emb_W = (const float*)d_in[4];
    P.Wioux = (const float*)d_in[5];
    P.bioux = (const float*)d_in[6];
    P.Wiouh = (const float*)d_in[7];
    P.biouh = (const float*)d_in[8];
    P.Wfx   = (const float*)d_in[9];
    P.bfx   = (const float*)d_in[10];
    P.Wfh   = (const float*)d_in[11];
    P.bfh   = (const float*)d_in[12];
    P.Wh    = (const float*)d_in[13];
    P.bh    = (const float*)d_in[14];
    P.Wp    = (const float*)d_in[15];
    P.bp    = (const float*)d_in[16];
    P.out   = (float*)d_out;

    char* w = (char*)d_ws;
    auto alloc = [&](size_t bytes) {
        char* r = w;
        w += (bytes + 255) & ~(size_t)255;
        return r;
    };
    // total ~142 MB
    P.E_ioux = (float*)alloc((size_t)VOCAB * G3 * 4);
    P.E_fx   = (float*)alloc((size_t)VOCAB * MD * 4);
    P.h_sum  = (float*)alloc((size_t)NN * MD * 4);
    P.fc_sum = (float*)alloc((size_t)NN * MD * 4);
    P.c_root = (float*)alloc(2 * MD * 4);
    P.anc_a  = (int*)alloc((size_t)TWO_N * 4);
    P.anc_b  = (int*)alloc((size_t)TWO_N * 4);
    P.dep_a  = (int*)alloc((size_t)TWO_N * 4);
    P.dep_b  = (int*)alloc((size_t)TWO_N * 4);
    P.cnt    = (int*)alloc((size_t)2 * DMAX * 4);
    P.offs   = (int*)alloc((size_t)2 * DMAX * 4);
    P.cur    = (int*)alloc((size_t)2 * DMAX * 4);
    P.order  = (int*)alloc((size_t)TWO_N * 4);
    P.maxd   = (int*)alloc(256);
    P.bar    = (int*)alloc(8192);

    // barrier counters must start at 0 each call
    hipMemsetAsync(P.bar, 0, 8192, stream);

    fused_kernel<<<dim3(NBLK), dim3(NT), 0, stream>>>(P);
}

// Round 8
// 7077.111 us; speedup vs baseline: 1.5213x; 1.3295x over previous
//
#include <hip/hip_runtime.h>
#include <math.h>

#define NN 65536
#define TWO_N (2 * NN)
#define VOCAB 1000
#define MD 256
#define G3 768
#define DMAX 65536
#define DCAP 128
#define NB 16
#define NT 256
#define NGRP 32

struct Params {
    const int* l_tokens; const int* l_parent;
    const int* r_tokens; const int* r_parent;
    const float* emb_W;
    const float* Wioux; const float* bioux;
    const float* Wiouh; const float* biouh;
    const float* Wfx;   const float* bfx;
    const float* Wfh;   const float* bfh;
    const float* Wh;    const float* bh;
    const float* Wp;    const float* bp;
    float* out;
    // workspace
    float* E_ioux;   // [VOCAB][768]
    float* E_fx;     // [VOCAB][256]
    float* h_sum;    // [NN][256]  (one tree at a time)
    float* fc_sum;   // [NN][256]
    float* c_root;   // [2][256]
    int* anc_a; int* anc_b; int* dep_a; int* dep_b;  // [2N]
    int* cnt; int* offs; int* cur;                    // [2*DMAX]
    int* order;                                        // [2N]
    int* maxd;                                         // [2] + flags[16]
    int* bar;                                          // barrier region (memset 0)
};

union SMem {
    struct { float es[4][MD]; } e;
    struct {
        float hls[NB][MD];
        int nid[NB]; int loc[NB]; int tok[NB]; int par[NB]; int ptok[NB];
    } w;
    struct { int hcnt[2 * DCAP]; int hbase[2 * DCAP]; int hmax2[2]; } s;
    struct { float vec[2 * MD]; float red[2][NT]; } h;
};

__device__ __forceinline__ float sigmoidf_(float x) {
    return 1.0f / (1.0f + __expf(-x));
}
__device__ __forceinline__ float tanhf_(float x) {
    float ex = __expf(2.0f * x);
    return 1.0f - 2.0f / (ex + 1.0f);
}

// ---- two-level monotonic grid barrier: NGRP groups x (nblk/NGRP) blocks ----
__device__ __forceinline__ int aload_(int* p) {
    return __hip_atomic_load(p, __ATOMIC_RELAXED, __HIP_MEMORY_SCOPE_AGENT);
}
__device__ void gbarrier(int* bar, int bid, int gsz, int ep) {
    __syncthreads();
    if (threadIdx.x == 0) {
        __builtin_amdgcn_fence(__ATOMIC_RELEASE, "agent");
        int g = bid / gsz;                       // group id 0..NGRP-1
        int* grpcnt = bar + g * 32;              // 128B-spaced counters
        int* rootcnt = bar + NGRP * 32;
        int* bcast  = bar + (NGRP + 1) * 32 + g * 32;
        int a = __hip_atomic_fetch_add(grpcnt, 1, __ATOMIC_RELAXED,
                                       __HIP_MEMORY_SCOPE_AGENT);
        if (a == gsz * ep - 1) {                 // last of my group this episode
            int r = __hip_atomic_fetch_add(rootcnt, 1, __ATOMIC_RELAXED,
                                           __HIP_MEMORY_SCOPE_AGENT);
            if (r == NGRP * ep - 1) {            // last overall: release
                for (int j = 0; j < NGRP; ++j)
                    __hip_atomic_store(bar + (NGRP + 1) * 32 + j * 32, ep,
                                       __ATOMIC_RELAXED, __HIP_MEMORY_SCOPE_AGENT);
            } else {
                while (aload_(bcast) < ep) __builtin_amdgcn_s_sleep(2);
            }
        } else {
            while (aload_(bcast) < ep) __builtin_amdgcn_s_sleep(2);
        }
        __builtin_amdgcn_fence(__ATOMIC_ACQUIRE, "agent");
    }
    __syncthreads();
}

// processes NB nodes of ONE tree; state arrays are local-indexed [NN][256]
__device__ void process_group(const Params& P, SMem& sm, int base, int cntv, int t) {
    __syncthreads();
    if (t < NB) {
        int g = -1, loc = 0, tok = 0, par = 0, ptok = 0;
        if (t < cntv) {
            g = P.order[base + t];
            int tree = g >> 16, i = g & (NN - 1);
            const int* toks = tree ? P.r_tokens : P.l_tokens;
            const int* pars = tree ? P.r_parent : P.l_parent;
            loc = i;
            tok = toks[i];
            int pl = pars[i];
            par = pl;
            ptok = toks[pl];
        }
        sm.w.nid[t] = g; sm.w.loc[t] = loc; sm.w.tok[t] = tok;
        sm.w.par[t] = par; sm.w.ptok[t] = ptok;
    }
    __syncthreads();
    #pragma unroll
    for (int nb = 0; nb < NB; ++nb) {
        int g = sm.w.nid[nb];
        sm.w.hls[nb][t] = (g >= 0) ? P.h_sum[(size_t)sm.w.loc[nb] * MD + t] : 0.0f;
    }
    __syncthreads();

    // ---- iou = E_ioux[tok] + h_sum @ Wiouh + biouh ----
    float ai[NB], ao[NB], au[NB];
    #pragma unroll
    for (int nb = 0; nb < NB; ++nb) { ai[nb] = 0.f; ao[nb] = 0.f; au[nb] = 0.f; }
    const float* W = P.Wiouh;
    #pragma unroll 2
    for (int k = 0; k < MD; k += 4) {
        float wi0 = W[(k + 0) * G3 + t];
        float wi1 = W[(k + 1) * G3 + t];
        float wi2 = W[(k + 2) * G3 + t];
        float wi3 = W[(k + 3) * G3 + t];
        float wo0 = W[(k + 0) * G3 + 256 + t];
        float wo1 = W[(k + 1) * G3 + 256 + t];
        float wo2 = W[(k + 2) * G3 + 256 + t];
        float wo3 = W[(k + 3) * G3 + 256 + t];
        float wu0 = W[(k + 0) * G3 + 512 + t];
        float wu1 = W[(k + 1) * G3 + 512 + t];
        float wu2 = W[(k + 2) * G3 + 512 + t];
        float wu3 = W[(k + 3) * G3 + 512 + t];
        #pragma unroll
        for (int nb = 0; nb < NB; ++nb) {
            float4 hv = *(const float4*)&sm.w.hls[nb][k];
            ai[nb] += wi0 * hv.x; ai[nb] += wi1 * hv.y; ai[nb] += wi2 * hv.z; ai[nb] += wi3 * hv.w;
            ao[nb] += wo0 * hv.x; ao[nb] += wo1 * hv.y; ao[nb] += wo2 * hv.z; ao[nb] += wo3 * hv.w;
            au[nb] += wu0 * hv.x; au[nb] += wu1 * hv.y; au[nb] += wu2 * hv.z; au[nb] += wu3 * hv.w;
        }
    }

    // ---- gates, c, h ----
    float cv[NB];
    float b_i = P.biouh[t], b_o = P.biouh[256 + t], b_u = P.biouh[512 + t];
    __syncthreads();
    #pragma unroll
    for (int nb = 0; nb < NB; ++nb) {
        int g = sm.w.nid[nb];
        float hval = 0.0f, cval = 0.0f;
        if (g >= 0) {
            const float* Ei = P.E_ioux + (size_t)sm.w.tok[nb] * G3;
            float ig = Ei[t] + ai[nb] + b_i;
            float og = Ei[256 + t] + ao[nb] + b_o;
            float ug = Ei[512 + t] + au[nb] + b_u;
            cval = sigmoidf_(ig) * tanhf_(ug) + P.fc_sum[(size_t)sm.w.loc[nb] * MD + t];
            hval = sigmoidf_(og) * tanhf_(cval);
        }
        cv[nb] = cval;
        sm.w.hls[nb][t] = hval;
    }
    __syncthreads();

    // ---- f = sigmoid(h @ Wfh + bfh + E_fx[ptok]) ; scatter to parent ----
    float af[NB];
    #pragma unroll
    for (int nb = 0; nb < NB; ++nb) af[nb] = 0.f;
    const float* Wf = P.Wfh;
    #pragma unroll 2
    for (int k = 0; k < MD; k += 4) {
        float wf0 = Wf[(k + 0) * MD + t];
        float wf1 = Wf[(k + 1) * MD + t];
        float wf2 = Wf[(k + 2) * MD + t];
        float wf3 = Wf[(k + 3) * MD + t];
        #pragma unroll
        for (int nb = 0; nb < NB; ++nb) {
            float4 hv = *(const float4*)&sm.w.hls[nb][k];
            af[nb] += wf0 * hv.x; af[nb] += wf1 * hv.y; af[nb] += wf2 * hv.z; af[nb] += wf3 * hv.w;
        }
    }
    float b_f = P.bfh[t];
    #pragma unroll
    for (int nb = 0; nb < NB; ++nb) {
        int g = sm.w.nid[nb];
        if (g < 0) continue;
        int i = g & (NN - 1);
        if (i == 0) {
            P.c_root[(g >> 16) * MD + t] = cv[nb];
        } else {
            float f = sigmoidf_(af[nb] + b_f + P.E_fx[(size_t)sm.w.ptok[nb] * MD + t]);
            int p = sm.w.par[nb];
            atomicAdd(&P.h_sum[(size_t)p * MD + t], sm.w.hls[nb][t]);
            atomicAdd(&P.fc_sum[(size_t)p * MD + t], f * cv[nb]);
        }
    }
}

__device__ void etab_body(const Params& P, SMem& sm, int t, int bid, int nblk) {
    for (int v0 = bid * 4; v0 < VOCAB; v0 += nblk * 4) {
        __syncthreads();
        #pragma unroll
        for (int r = 0; r < 4; ++r)
            sm.e.es[r][t] = (v0 + r < VOCAB) ? P.emb_W[(size_t)(v0 + r) * MD + t] : 0.f;
        __syncthreads();
        float a0[4] = {0.f,0.f,0.f,0.f}, a1[4] = {0.f,0.f,0.f,0.f};
        float a2[4] = {0.f,0.f,0.f,0.f}, a3[4] = {0.f,0.f,0.f,0.f};
        for (int k = 0; k < MD; ++k) {
            float wi = P.Wioux[k * G3 + t];
            float wo = P.Wioux[k * G3 + 256 + t];
            float wu = P.Wioux[k * G3 + 512 + t];
            float wf = P.Wfx[k * MD + t];
            #pragma unroll
            for (int r = 0; r < 4; ++r) {
                float e = sm.e.es[r][k];
                a0[r] += wi * e; a1[r] += wo * e; a2[r] += wu * e; a3[r] += wf * e;
            }
        }
        float bi = P.bioux[t], bo = P.bioux[256 + t], bu = P.bioux[512 + t], bf = P.bfx[t];
        for (int r = 0; r < 4; ++r) {
            if (v0 + r < VOCAB) {
                P.E_ioux[(size_t)(v0 + r) * G3 + t]       = a0[r] + bi;
                P.E_ioux[(size_t)(v0 + r) * G3 + 256 + t] = a1[r] + bo;
                P.E_ioux[(size_t)(v0 + r) * G3 + 512 + t] = a2[r] + bu;
                P.E_fx[(size_t)(v0 + r) * MD + t]         = a3[r] + bf;
            }
        }
        __syncthreads();
    }
}

__device__ void head_body(const Params& P, SMem& sm, int t) {
    float cl = P.c_root[t], cr = P.c_root[MD + t];
    sm.h.vec[t] = cl * cr;
    sm.h.vec[MD + t] = fabsf(cl - cr);
    __syncthreads();
    float acc = 0.f;
    for (int j = 0; j < 2 * MD; ++j) acc += sm.h.vec[j] * P.Wh[(size_t)j * MD + t];
    float hid = sigmoidf_(acc + P.bh[t]);
    sm.h.red[0][t] = hid * P.Wp[t * 2 + 0];
    sm.h.red[1][t] = hid * P.Wp[t * 2 + 1];
    __syncthreads();
    for (int s = 128; s > 0; s >>= 1) {
        if (t < s) {
            sm.h.red[0][t] += sm.h.red[0][t + s];
            sm.h.red[1][t] += sm.h.red[1][t + s];
        }
        __syncthreads();
    }
    if (t == 0) {
        float l0 = sm.h.red[0][0] + P.bp[0];
        float l1 = sm.h.red[1][0] + P.bp[1];
        float mx = fmaxf(l0, l1);
        float e0 = __expf(l0 - mx), e1 = __expf(l1 - mx);
        float inv = 1.0f / (e0 + e1);
        P.out[0] = e0 * inv;
        P.out[1] = e1 * inv;
    }
}

// =======================================================================
// Persistent fused kernel: grid = occupancy-safe co-resident block count.
// =======================================================================
__global__ __launch_bounds__(NT, 4) void fused_kernel(Params P) {
    __shared__ SMem sm;
    const int t = threadIdx.x;
    const int bid = blockIdx.x;
    const int nblk = gridDim.x;
    const int gsz = nblk / NGRP;
    const int gsize = nblk * NT;
    const int gtid = bid * NT + t;
    int* flags = P.maxd + 2;
    int ep = 0;

    // ---- phase A: zero state & counters, init anc/dep ----
    {
        float4 z = make_float4(0.f, 0.f, 0.f, 0.f);
        float4* hz = (float4*)P.h_sum;
        float4* fz = (float4*)P.fc_sum;
        int n4 = NN * (MD / 4);
        for (int i = gtid; i < n4; i += gsize) { hz[i] = z; fz[i] = z; }
        for (int i = gtid; i < 2 * DMAX; i += gsize) { P.cnt[i] = 0; P.cur[i] = 0; }
        if (gtid < 2) P.maxd[gtid] = 0;
        if (gtid >= 2 && gtid < 18) flags[gtid - 2] = 0;
        for (int g = gtid; g < TWO_N; g += gsize) {
            int tree = g >> 16, i = g & (NN - 1);
            if (i == 0) { P.anc_a[g] = g; P.dep_a[g] = 0; }
            else {
                const int* par = tree ? P.r_parent : P.l_parent;
                P.anc_a[g] = (tree << 16) | par[i];
                P.dep_a[g] = 1;
            }
        }
    }
    // ---- phase B: E tables ----
    etab_body(P, sm, t, bid, nblk);
    gbarrier(P.bar, bid, gsz, ++ep);

    // ---- phase C: pointer doubling, early exit ----
    {
        int* pa = P.anc_a; int* pd = P.dep_a; int* qa = P.anc_b; int* qd = P.dep_b;
        for (int it = 0; it < 16; ++it) {
            int changed = 0;
            for (int g = gtid; g < TWO_N; g += gsize) {
                int a = pa[g];
                int da = pd[a];
                qd[g] = pd[g] + da;
                qa[g] = pa[a];
                changed |= (da != 0);
            }
            if (changed) flags[it] = 1;
            gbarrier(P.bar, bid, gsz, ++ep);
            int* tmp = pa; pa = qa; qa = tmp;
            tmp = pd; pd = qd; qd = tmp;
            if (flags[it] == 0) break;    // uniform
        }
        if (pd != P.dep_a) {
            for (int g = gtid; g < TWO_N; g += gsize) P.dep_a[g] = pd[g];
            gbarrier(P.bar, bid, gsz, ++ep);
        }
    }

    // ---- phase D: hist ----
    {
        for (int i = t; i < 2 * DCAP; i += NT) sm.s.hcnt[i] = 0;
        if (t < 2) sm.s.hmax2[t] = 0;
        __syncthreads();
        for (int g = gtid; g < TWO_N; g += gsize) {
            int tree = g >> 16;
            int d = P.dep_a[g];
            if (d < DCAP) {
                atomicAdd(&sm.s.hcnt[tree * DCAP + d], 1);
                atomicMax(&sm.s.hmax2[tree], d);
            } else {
                atomicAdd(&P.cnt[tree * DMAX + d], 1);
                atomicMax(&P.maxd[tree], d);
            }
        }
        __syncthreads();
        for (int i = t; i < 2 * DCAP; i += NT) {
            int c = sm.s.hcnt[i];
            if (c > 0) atomicAdd(&P.cnt[(i >= DCAP ? DMAX : 0) + (i & (DCAP - 1))], c);
        }
        if (t < 2) atomicMax(&P.maxd[t], sm.s.hmax2[t]);
    }
    gbarrier(P.bar, bid, gsz, ++ep);

    // ---- prefix (block 0) ----
    if (bid == 0 && t < 2) {
        int tree = t;
        int run = tree * NN;
        int md = P.maxd[tree];
        for (int d = 0; d <= md; ++d) {
            P.offs[tree * DMAX + d] = run;
            run += P.cnt[tree * DMAX + d];
        }
    }
    gbarrier(P.bar, bid, gsz, ++ep);

    // ---- scatter ----
    {
        for (int i = t; i < 2 * DCAP; i += NT) sm.s.hcnt[i] = 0;
        __syncthreads();
        for (int g = gtid; g < TWO_N; g += gsize) {
            int tree = g >> 16;
            int d = P.dep_a[g];
            if (d < DCAP) atomicAdd(&sm.s.hcnt[tree * DCAP + d], 1);
        }
        __syncthreads();
        for (int i = t; i < 2 * DCAP; i += NT) {
            int c = sm.s.hcnt[i];
            if (c > 0) {
                int idx = (i >= DCAP ? DMAX : 0) + (i & (DCAP - 1));
                sm.s.hbase[i] = P.offs[idx] + atomicAdd(&P.cur[idx], c);
            }
            sm.s.hcnt[i] = 0;
        }
        __syncthreads();
        for (int g = gtid; g < TWO_N; g += gsize) {
            int tree = g >> 16;
            int d = P.dep_a[g];
            if (d < DCAP) {
                int b = tree * DCAP + d;
                int pos = atomicAdd(&sm.s.hcnt[b], 1);
                P.order[sm.s.hbase[b] + pos] = g;
            } else {
                int idx = tree * DMAX + d;
                int pos = atomicAdd(&P.cur[idx], 1);
                P.order[P.offs[idx] + pos] = g;
            }
        }
    }
    gbarrier(P.bar, bid, gsz, ++ep);

    // ---- depth ladders ----
    for (int tree = 0; tree < 2; ++tree) {
        int md = P.maxd[tree];
        for (int d = md; d >= 0; --d) {
            int nwave = P.cnt[tree * DMAX + d];
            int start = P.offs[tree * DMAX + d];
            int ngroups = (nwave + NB - 1) / NB;
            for (int grp = bid; grp < ngroups; grp += nblk) {
                int base = grp * NB;
                int cntv = nwave - base; if (cntv > NB) cntv = NB;
                process_group(P, sm, start + base, cntv, t);
            }
            gbarrier(P.bar, bid, gsz, ++ep);
        }
        if (tree == 0) {
            float4 z = make_float4(0.f, 0.f, 0.f, 0.f);
            float4* hz = (float4*)P.h_sum;
            float4* fz = (float4*)P.fc_sum;
            int n4 = NN * (MD / 4);
            for (int i = gtid; i < n4; i += gsize) { hz[i] = z; fz[i] = z; }
            gbarrier(P.bar, bid, gsz, ++ep);
        }
    }

    // ---- head ----
    if (bid == 0) head_body(P, sm, t);
}

extern "C" void kernel_launch(void* const* d_in, const int* in_sizes, int n_in,
                              void* d_out, int out_size, void* d_ws, size_t ws_size,
                              hipStream_t stream) {
    Params P;
    P.l_tokens = (const int*)d_in[0];
    P.l_parent = (const int*)d_in[1];
    P.r_tokens = (const int*)d_in[2];
    P.r_parent = (const int*)d_in[3];
    P.emb_W = (const float*)d_in[4];
    P.Wioux = (const float*)d_in[5];
    P.bioux = (const float*)d_in[6];
    P.Wiouh = (const float*)d_in[7];
    P.biouh = (const float*)d_in[8];
    P.Wfx   = (const float*)d_in[9];
    P.bfx   = (const float*)d_in[10];
    P.Wfh   = (const float*)d_in[11];
    P.bfh   = (const float*)d_in[12];
    P.Wh    = (const float*)d_in[13];
    P.bh    = (const float*)d_in[14];
    P.Wp    = (const float*)d_in[15];
    P.bp    = (const float*)d_in[16];
    P.out   = (float*)d_out;

    char* w = (char*)d_ws;
    auto alloc = [&](size_t bytes) {
        char* r = w;
        w += (bytes + 255) & ~(size_t)255;
        return r;
    };
    // total ~142 MB
    P.E_ioux = (float*)alloc((size_t)VOCAB * G3 * 4);
    P.E_fx   = (float*)alloc((size_t)VOCAB * MD * 4);
    P.h_sum  = (float*)alloc((size_t)NN * MD * 4);
    P.fc_sum = (float*)alloc((size_t)NN * MD * 4);
    P.c_root = (float*)alloc(2 * MD * 4);
    P.anc_a  = (int*)alloc((size_t)TWO_N * 4);
    P.anc_b  = (int*)alloc((size_t)TWO_N * 4);
    P.dep_a  = (int*)alloc((size_t)TWO_N * 4);
    P.dep_b  = (int*)alloc((size_t)TWO_N * 4);
    P.cnt    = (int*)alloc((size_t)2 * DMAX * 4);
    P.offs   = (int*)alloc((size_t)2 * DMAX * 4);
    P.cur    = (int*)alloc((size_t)2 * DMAX * 4);
    P.order  = (int*)alloc((size_t)TWO_N * 4);
    P.maxd   = (int*)alloc(256);
    P.bar    = (int*)alloc(16384);

    // barrier counters must start at 0 each call
    hipMemsetAsync(P.bar, 0, 16384, stream);

    // occupancy-safe co-resident grid (pure query: capture-safe, deterministic)
    int bpc = 1;
    hipOccupancyMaxActiveBlocksPerMultiprocessor(&bpc, (const void*)fused_kernel,
                                                 NT, 0);
    if (bpc < 1) bpc = 1;
    if (bpc > 4) bpc = 4;
    int nblk = 256 * bpc;            // multiple of NGRP(32)

    fused_kernel<<<dim3(nblk), dim3(NT), 0, stream>>>(P);
}